// Round 1
// 1131.185 us; speedup vs baseline: 1.3855x; 1.3855x over previous
//
#include <hip/hip_runtime.h>
#include <hip/hip_bf16.h>

// ---------------------------------------------------------------------------
// SelfAttentionModule: concat(f_rgb,f_i) -> 1x1 conv Q,K,V -> softmax(QK^T/64)
// -> V @ attn^T -> fold halves.
// Outputs (flat, in order): f_final [2,2048,64,64], f_rgb copy, f_i copy,
//                           attn [2,4096,4096].
// GEMMs now use the 256x256 8-phase counted-vmcnt template (T2+T3+T4+T5):
//   - BM=BN=256, BK=64, 512 threads (8 waves, 2M x 4N), per-wave C = 128x64
//   - 128 KiB LDS, double-buffered; global_load_lds with linear dest +
//     inverse-swizzled source (col ^= (row&7)<<4) = conflict-free ds_read_b128
//   - 4 phases per K-tile, 1 C-quadrant (16 MFMA) per phase, frag reuse
//     (24 ds_read_b128 per tile per wave), s_setprio(1) around MFMA
//   - vmcnt(4) only at K-tile boundaries (2 half-tiles stay in flight)
// ---------------------------------------------------------------------------

#define B_   2
#define C_   2048
#define N_   4096
#define C2_  4096

#define LDSB 131072   // 2 dbuf x (A 32KB + B 32KB)

typedef __hip_bfloat16 bf16_t;
typedef __bf16 bf16x8 __attribute__((ext_vector_type(8)));
typedef float floatx4 __attribute__((ext_vector_type(4)));

__device__ inline void load_lds16(const void* g, void* l) {
  __builtin_amdgcn_global_load_lds(
      (const __attribute__((address_space(1))) void*)g,
      (__attribute__((address_space(3))) void*)l, 16, 0, 0);
}

__device__ inline unsigned short f2bf(float f) {
  return __builtin_bit_cast(unsigned short, __float2bfloat16(f));
}

__device__ inline void cstore(float* p, float v)  { *p = v; }
__device__ inline void cstore(bf16_t* p, float v) { *p = __float2bfloat16(v); }

// ---------------------------------------------------------------------------
// 8-phase 256^2 GEMM: C[i][j] = scale*sum_k A[i][k]*Bt[j][k] + bias_m + bias_n
// M,N multiples of 256; K multiple of 64. grid = (N/256, M/256, batch),
// 512 threads, dynamic LDS = 131072 B.
// Wave (wm=wave>>2, wn=wave&3). M-frags interleaved: rows mi*32+wm*16
// (mi=0..7); N-frags: cols ni*64+wn*16 (ni=0..3). Quadrant (mh,nh) covers
// mi in [mh*4,mh*4+4), ni in [nh*2,nh*2+2)  -> A-half mh, B-half nh only.
// LDS tile layout (per matrix, per buffer): [256 rows][64 k] bf16, row=128B,
// stored byte = row*128 + (colByte ^ ((row&7)<<4)); staged linearly with the
// same involution applied to the SOURCE column (rule #21).
// ---------------------------------------------------------------------------
template <typename OutT>
__global__ __launch_bounds__(512, 2) void gemm_bt8(
    const bf16_t* __restrict__ A, const bf16_t* __restrict__ Bt,
    OutT* __restrict__ Cm, int K, int lda, int ldb, int ldc,
    long long abst, long long bbst, long long cbst,
    const float* __restrict__ bias_m, const float* __restrict__ bias_n,
    float scale)
{
  extern __shared__ char smem[];   // [2][A|B][256*64] bf16 = 131072 B

  const int tid  = threadIdx.x;
  const int lane = tid & 63;
  const int wave = tid >> 6;        // 0..7
  const int wm   = wave >> 2;       // 0..1 (M)
  const int wn   = wave & 3;        // 0..3 (N)
  const int fr   = lane & 15;       // fragment row/col
  const int kc   = lane >> 4;       // 0..3 k-chunk

  const long long bM = (long long)blockIdx.y * 256;
  const long long bN = (long long)blockIdx.x * 256;

  const bf16_t* Ab = A  + (long long)blockIdx.z * abst;
  const bf16_t* Bb = Bt + (long long)blockIdx.z * bbst;
  OutT*         Cb = Cm + (long long)blockIdx.z * cbst;

  // ---- staging geometry ----
  // thread covers row (wave*8 + lane>>3) of each 64-row issue block;
  // source col pre-swizzled so linear LDS dest == swizzled layout.
  const int srow = lane >> 3;                   // 0..7 ; == row&7 always
  const int scol = 8 * ((lane & 7) ^ srow);     // swizzled k-elem offset
  const bf16_t* gA = Ab + (bM + wave * 8 + srow) * (long long)lda + scol;
  const bf16_t* gB = Bb + (bN + wave * 8 + srow) * (long long)ldb + scol;
  char* sbase = smem + wave * 1024;             // wave-uniform (+lane*16 by HW)

  // stage half-tile h (rows h*128..h*128+127) of K-tile kt into buffer p.
  // ab: 0 = A, 1 = B. 2 x global_load_lds_dwordx4 per thread.
  auto stage = [&](int p, int ab, int h, int kt) {
    const long long ld = ab ? ldb : lda;
    const bf16_t* g = (ab ? gB : gA) + (long long)h * 128 * ld
                                     + (long long)kt * 64;
    char* l = sbase + p * 65536 + ab * 32768 + h * 16384;
    load_lds16(g,            l);
    load_lds16(g + 64 * ld,  l + 8192);
  };

  floatx4 acc[8][4];
#pragma unroll
  for (int i = 0; i < 8; i++)
#pragma unroll
    for (int j = 0; j < 4; j++) acc[i][j] = (floatx4){0.f, 0.f, 0.f, 0.f};

  bf16x8 af[4][2];    // current A-half frags  [mi-local][kstep]
  bf16x8 bfr[4][2];   // ALL B frags kept live [ni][kstep]

  // read A-half mh of buffer p into af (8 x ds_read_b128)
  auto readAh = [&](int p, int mh) {
#pragma unroll
    for (int i = 0; i < 4; i++) {
      const int row = (mh * 4 + i) * 32 + wm * 16 + fr;   // row&7 == fr&7
      const char* rb = smem + p * 65536 + row * 128;
#pragma unroll
      for (int ks = 0; ks < 2; ks++)
        af[i][ks] = *(const bf16x8*)(rb +
            (((ks * 64) + kc * 16) ^ ((fr & 7) << 4)));
    }
  };
  // read B-half nh of buffer p into bfr[nh*2..nh*2+1] (4 x ds_read_b128)
  auto readBh = [&](int p, int nh) {
#pragma unroll
    for (int j = 0; j < 2; j++) {
      const int row = (nh * 2 + j) * 64 + wn * 16 + fr;
      const char* rb = smem + p * 65536 + 32768 + row * 128;
#pragma unroll
      for (int ks = 0; ks < 2; ks++)
        bfr[nh * 2 + j][ks] = *(const bf16x8*)(rb +
            (((ks * 64) + kc * 16) ^ ((fr & 7) << 4)));
    }
  };
  // one C-quadrant: 16 MFMA, prio-boosted (T5)
  auto quad = [&](int mh, int nh) {
    __builtin_amdgcn_s_setprio(1);
#pragma unroll
    for (int i = 0; i < 4; i++)
#pragma unroll
      for (int j = 0; j < 2; j++)
#pragma unroll
        for (int ks = 0; ks < 2; ks++)
          acc[mh * 4 + i][nh * 2 + j] = __builtin_amdgcn_mfma_f32_16x16x32_bf16(
              af[i][ks], bfr[nh * 2 + j][ks], acc[mh * 4 + i][nh * 2 + j],
              0, 0, 0);
    __builtin_amdgcn_s_setprio(0);
  };

  const int NT = K >> 6;

  // prologue: T0 complete + T1.{A0,B0}  (12 gload instructions)
  {
    const int t1 = (NT > 1) ? 1 : 0;
    stage(0, 0, 0, 0); stage(0, 1, 0, 0);
    stage(0, 0, 1, 0); stage(0, 1, 1, 0);
    stage(1, 0, 0, t1); stage(1, 1, 0, t1);
  }
  asm volatile("s_waitcnt vmcnt(4)" ::: "memory");   // T0 landed
  __builtin_amdgcn_s_barrier();

  for (int t = 0; t < NT; ++t) {
    const int p  = t & 1, q = p ^ 1;
    const int t1 = (t + 1 < NT) ? t + 1 : NT - 1;    // clamped (dead writes ok)
    const int t2 = (t + 2 < NT) ? t + 2 : NT - 1;

    // phase 1: quadrant (0,0) — read A0 + B0 (12 reads), stage (t+1).A1 -> q
    readAh(p, 0); readBh(p, 0);
    stage(q, 0, 1, t1);
    __builtin_amdgcn_s_barrier();
    quad(0, 0);
    __builtin_amdgcn_s_barrier();

    // phase 2: (0,1) — read B1 (4 reads), stage (t+1).B1 -> q
    readBh(p, 1);
    stage(q, 1, 1, t1);
    __builtin_amdgcn_s_barrier();
    quad(0, 1);
    __builtin_amdgcn_s_barrier();

    // phase 3: (1,1) — read A1 (8 reads), stage (t+2).A0 -> p (A0 retired ph1)
    readAh(p, 1);
    stage(p, 0, 0, t2);
    __builtin_amdgcn_s_barrier();
    quad(1, 1);
    __builtin_amdgcn_s_barrier();

    // phase 4: (1,0) — no reads (af=A1, bfr[0..1]=B0), stage (t+2).B0 -> p
    stage(p, 1, 0, t2);
    __builtin_amdgcn_s_barrier();
    quad(1, 0);
    // K-tile boundary: all of tile t+1 landed; (t+2).{A0,B0} stay in flight
    asm volatile("s_waitcnt vmcnt(4)" ::: "memory");
    __builtin_amdgcn_s_barrier();
  }

  // epilogue: C/D layout col=lane&15, row=(lane>>4)*4+r  [m89-verified]
  const int rown = (lane >> 4) * 4;
#pragma unroll
  for (int mi = 0; mi < 8; mi++) {
#pragma unroll
    for (int ni = 0; ni < 4; ni++) {
      const long long n = bN + ni * 64 + wn * 16 + fr;
      const float bnv = bias_n ? bias_n[n] : 0.f;
#pragma unroll
      for (int r = 0; r < 4; r++) {
        const long long m = bM + mi * 32 + wm * 16 + rown + r;
        const float bmv = bias_m ? bias_m[m] : 0.f;
        cstore(&Cb[m * (long long)ldc + n], acc[mi][ni][r] * scale + bnv + bmv);
      }
    }
  }
}

// ---------------------------------------------------------------------------
// pack_xt: per 64(c)x64(n) tile of one source (z = b*2 + which):
//   read fp32 coalesced, write passthrough copy, LDS-transpose, write Xt bf16.
// ---------------------------------------------------------------------------
__global__ __launch_bounds__(256) void pack_xt(
    const float* __restrict__ f_rgb, const float* __restrict__ f_i,
    float* __restrict__ out_rgb, float* __restrict__ out_i,
    bf16_t* __restrict__ xt)
{
  const int b  = blockIdx.z >> 1;
  const int wh = blockIdx.z & 1;
  const float* src = (wh ? f_i : f_rgb) + (long long)b * C_ * N_;
  float*       pt  = (wh ? out_i : out_rgb) + (long long)b * C_ * N_;
  const int c0 = blockIdx.y * 64, n0 = blockIdx.x * 64;
  __shared__ float tile[64][65];

  const int tid = threadIdx.x;
  {
    const int tn = tid & 63, tc4 = tid >> 6;
#pragma unroll
    for (int r = 0; r < 16; r++) {
      const int c = tc4 * 16 + r;
      const long long idx = (long long)(c0 + c) * N_ + n0 + tn;
      const float v = src[idx];
      pt[idx] = v;
      tile[tn][c] = v;
    }
  }
  __syncthreads();
  {
    const int tc = tid & 63, tn4 = tid >> 6;
#pragma unroll
    for (int r = 0; r < 16; r++) {
      const int n = tn4 * 16 + r;
      xt[((long long)b * N_ + n0 + n) * C2_ + wh * C_ + c0 + tc] =
          __float2bfloat16(tile[n][tc]);
    }
  }
}

// wqk_bf[o][c]: rows 0..2047 = wq, 2048..4095 = wk (bf16)
__global__ __launch_bounds__(256) void conv_wqk(
    const float* __restrict__ wq, const float* __restrict__ wk,
    unsigned short* __restrict__ dst)
{
  const long long i = ((long long)blockIdx.x * 256 + threadIdx.x) * 4;
  const int o = (int)(i >> 12);
  const long long c = i & 4095;
  const float* src = (o < C_) ? (wq + (long long)o * C2_ + c)
                              : (wk + (long long)(o - C_) * C2_ + c);
  const float4 f = *(const float4*)src;
  *(ushort4*)(dst + i) = make_ushort4(f2bf(f.x), f2bf(f.y), f2bf(f.z), f2bf(f.w));
}

// wvsum_bf[c][c2] = bf16(wv[c][c2] + wv[c+2048][c2])
__global__ __launch_bounds__(256) void conv_wvsum(
    const float* __restrict__ wv, unsigned short* __restrict__ dst)
{
  const long long i = ((long long)blockIdx.x * 256 + threadIdx.x) * 4;
  const float4 a = *(const float4*)(wv + i);
  const float4 b = *(const float4*)(wv + i + (long long)C_ * C2_);
  *(ushort4*)(dst + i) = make_ushort4(f2bf(a.x + b.x), f2bf(a.y + b.y),
                                      f2bf(a.z + b.z), f2bf(a.w + b.w));
}

__global__ __launch_bounds__(256) void conv_bias(
    const float* __restrict__ bq, const float* __restrict__ bk,
    const float* __restrict__ bv, float* __restrict__ bqk,
    float* __restrict__ bvsum)
{
  const int i = blockIdx.x * 256 + threadIdx.x;   // < 4096
  bqk[i] = (i < C_) ? bq[i] : bk[i - C_];
  if (i < C_) bvsum[i] = bv[i] + bv[i + C_];
}

// in-place row softmax on d_out attn region + bf16 copy. 1 block per row.
__global__ __launch_bounds__(256) void softmax_rows(
    float* __restrict__ attn, bf16_t* __restrict__ attn_bf)
{
  const long long row = blockIdx.x;   // 0 .. B*N-1
  float*  p  = attn    + row * N_;
  bf16_t* pb = attn_bf + row * N_;
  const int tid = threadIdx.x;
  const int lane = tid & 63, wave = tid >> 6;

  float v[16];
  float mx = -3.4e38f;
#pragma unroll
  for (int i = 0; i < 16; i++) { v[i] = p[tid + i * 256]; mx = fmaxf(mx, v[i]); }
#pragma unroll
  for (int off = 32; off >= 1; off >>= 1) mx = fmaxf(mx, __shfl_xor(mx, off, 64));

  __shared__ float redm[4];
  __shared__ float reds[4];
  if (lane == 0) redm[wave] = mx;
  __syncthreads();
  mx = fmaxf(fmaxf(redm[0], redm[1]), fmaxf(redm[2], redm[3]));

  float s = 0.f;
#pragma unroll
  for (int i = 0; i < 16; i++) { v[i] = __expf(v[i] - mx); s += v[i]; }
#pragma unroll
  for (int off = 32; off >= 1; off >>= 1) s += __shfl_xor(s, off, 64);
  if (lane == 0) reds[wave] = s;
  __syncthreads();
  s = reds[0] + reds[1] + reds[2] + reds[3];
  const float inv = 1.f / s;
#pragma unroll
  for (int i = 0; i < 16; i++) {
    const float a = v[i] * inv;
    p[tid + i * 256]  = a;
    pb[tid + i * 256] = __float2bfloat16(a);
  }
}

extern "C" void kernel_launch(void* const* d_in, const int* in_sizes, int n_in,
                              void* d_out, int out_size, void* d_ws, size_t ws_size,
                              hipStream_t stream) {
  const float* f_rgb = (const float*)d_in[0];
  const float* f_i   = (const float*)d_in[1];
  const float* wq    = (const float*)d_in[2];
  const float* bq    = (const float*)d_in[3];
  const float* wk    = (const float*)d_in[4];
  const float* bk    = (const float*)d_in[5];
  const float* wv    = (const float*)d_in[6];
  const float* bv    = (const float*)d_in[7];

  float* out       = (float*)d_out;
  float* out_ff    = out;                                  // [2][2048][4096]
  float* out_rgb   = out + (size_t)B_ * C_ * N_;
  float* out_fi    = out_rgb + (size_t)B_ * C_ * N_;
  float* out_attn  = out_fi + (size_t)B_ * C_ * N_;        // [2][4096][4096]

  // workspace layout (256-B aligned)
  char* ws = (char*)d_ws;
  size_t off = 0;
  auto alloc = [&](size_t bytes) {
    size_t o = off; off += (bytes + 255) & ~(size_t)255; return o;
  };
  bf16_t* xt   = (bf16_t*)(ws + alloc((size_t)B_ * N_ * C2_ * 2));   // 64 MiB
  bf16_t* wqk  = (bf16_t*)(ws + alloc((size_t)C2_ * C2_ * 2));       // 32 MiB
  bf16_t* wvs  = (bf16_t*)(ws + alloc((size_t)C_ * C2_ * 2));        // 16 MiB
  bf16_t* qkt  = (bf16_t*)(ws + alloc((size_t)B_ * N_ * C2_ * 2));   // 64 MiB
  bf16_t* vsum = (bf16_t*)(ws + alloc((size_t)B_ * C_ * N_ * 2));    // 32 MiB
  bf16_t* abf  = (bf16_t*)(ws + alloc((size_t)B_ * N_ * N_ * 2));    // 64 MiB
  float*  bqk  = (float*)(ws + alloc((size_t)C2_ * 4));
  float*  bvs  = (float*)(ws + alloc((size_t)C_ * 4));
  (void)ws_size; (void)in_sizes; (void)n_in; (void)out_size;

  // allow 128 KiB dynamic LDS (one-time, host-side; not a stream op)
  static bool attr_done = false;
  if (!attr_done) {
    (void)hipFuncSetAttribute((const void*)&gemm_bt8<bf16_t>,
        hipFuncAttributeMaxDynamicSharedMemorySize, LDSB);
    (void)hipFuncSetAttribute((const void*)&gemm_bt8<float>,
        hipFuncAttributeMaxDynamicSharedMemorySize, LDSB);
    attr_done = true;
  }

  const dim3 blk(256);
  const dim3 blk8(512);

  // 1) pack + passthrough
  pack_xt<<<dim3(N_ / 64, C_ / 64, B_ * 2), blk, 0, stream>>>(
      f_rgb, f_i, out_rgb, out_fi, xt);
  // 2) weights/biases -> bf16 / folded
  conv_wqk<<<dim3((C2_ * C2_) / (4 * 256)), blk, 0, stream>>>(
      wq, wk, (unsigned short*)wqk);
  conv_wvsum<<<dim3((C_ * C2_) / (4 * 256)), blk, 0, stream>>>(
      wv, (unsigned short*)wvs);
  conv_bias<<<dim3(C2_ / 256), blk, 0, stream>>>(bq, bk, bv, bqk, bvs);

  const long long sNN = (long long)N_ * C2_;      // 16777216
  const long long sCN = (long long)C_ * N_;       // 8388608

  // 3) G1: QKt[b][n][0:4096] = Xt . wqk^T + bqk   (bf16 out)
  gemm_bt8<bf16_t><<<dim3(C2_ / 256, N_ / 256, B_), blk8, LDSB, stream>>>(
      xt, wqk, qkt, C2_, C2_, C2_, C2_, sNN, 0, sNN, nullptr, bqk, 1.0f);

  // 4) GV: Vsum[b][c][m] = wvsum . Xt^T + bvsum   (bf16 out)
  gemm_bt8<bf16_t><<<dim3(N_ / 256, C_ / 256, B_), blk8, LDSB, stream>>>(
      wvs, xt, vsum, C2_, C2_, C2_, N_, 0, sNN, sCN, bvs, nullptr, 1.0f);

  // 5) G2: S[b][n][m] = Qt . Kt^T / 64 -> d_out attn region (fp32)
  gemm_bt8<float><<<dim3(N_ / 256, N_ / 256, B_), blk8, LDSB, stream>>>(
      qkt, qkt + C_, out_attn, C_, C2_, C2_, N_, sNN, sNN, sNN,
      nullptr, nullptr, 1.0f / 64.0f);

  // 6) softmax rows (in place) + bf16 copy
  softmax_rows<<<dim3(B_ * N_), blk, 0, stream>>>(out_attn, abf);

  // 7) G3: f_final[b][c][n] = Vsum . attn_bf^T (fp32)
  gemm_bt8<float><<<dim3(N_ / 256, C_ / 256, B_), blk8, LDSB, stream>>>(
      vsum, abf, out_ff, N_, N_, N_, N_, sCN, sNN, sCN,
      nullptr, nullptr, 1.0f);
}